// Round 12
// baseline (1215.006 us; speedup 1.0000x reference)
//
#include <hip/hip_runtime.h>
#include <math.h>

#define BSZ 4
#define FCH 1024
#define SEQ 2048
#define ICH 2048
#define KW  5
#define EPSV 1e-5f
#define RPAD 2244   // 4 front zero-pad + 2048 rows + slack

typedef __attribute__((ext_vector_type(8))) short bf16x8;
typedef __attribute__((ext_vector_type(4))) float f32x4;
typedef __attribute__((ext_vector_type(4))) unsigned short us4;
typedef __attribute__((ext_vector_type(8))) unsigned short us8;

__device__ __forceinline__ unsigned short f2bf(float f) {
  union { float f; unsigned u; } v; v.f = f;
  unsigned r = v.u + 0x7fff + ((v.u >> 16) & 1);  // round-to-nearest-even
  return (unsigned short)(r >> 16);
}
__device__ __forceinline__ float bf2f(unsigned short u) {
  union { unsigned u; float f; } v; v.u = (unsigned)u << 16; return v.f;
}

__device__ __forceinline__ void gload_lds16(const void* g, void* l) {
  __builtin_amdgcn_global_load_lds(
      (const __attribute__((address_space(1))) void*)g,
      (__attribute__((address_space(3))) void*)l, 16, 0, 0);
}

// ---------------- input transpose + pos add:  [b][f][s] -> bf16 [b][4+s][f]
// pad rows 0..3 zeroed by the s0==0 blocks (fused zero_xpad).
__global__ __launch_bounds__(256) void addpos_T_kernel(
    const float* __restrict__ inp, const float* __restrict__ pos,
    unsigned short* __restrict__ X)
{
  __shared__ float t[64][65];
  const int s0 = blockIdx.x * 64, f0 = blockIdx.y * 64, b = blockIdx.z;
  const int a = threadIdx.x & 63, g = threadIdx.x >> 6;
  const float* ib = inp + (size_t)b * FCH * SEQ;
#pragma unroll
  for (int i = 0; i < 16; ++i) {
    const size_t o = (size_t)(f0 + g + i * 4) * SEQ + s0 + a;
    t[a][g + i * 4] = ib[o] + pos[o];
  }
  if (blockIdx.x == 0 && g == 0) {
#pragma unroll
    for (int r = 0; r < 4; ++r)
      X[(size_t)b * RPAD * FCH + (size_t)r * FCH + f0 + a] = 0;
  }
  __syncthreads();
#pragma unroll
  for (int i = 0; i < 16; ++i)
    X[(size_t)b * RPAD * FCH + (size_t)(4 + s0 + g + i * 4) * FCH + f0 + a] =
        f2bf(t[g + i * 4][a]);
}

// divisor [f][s] -> divT [s][f] fp32
__global__ __launch_bounds__(256) void transpose_div_kernel(
    const float* __restrict__ D, float* __restrict__ O)
{
  __shared__ float t[64][65];
  const int s0 = blockIdx.x * 64, f0 = blockIdx.y * 64;
  const int a = threadIdx.x & 63, g = threadIdx.x >> 6;
#pragma unroll
  for (int i = 0; i < 16; ++i)
    t[a][g + i * 4] = D[(size_t)(f0 + g + i * 4) * SEQ + s0 + a];
  __syncthreads();
#pragma unroll
  for (int i = 0; i < 16; ++i)
    O[(size_t)(s0 + g + i * 4) * FCH + f0 + a] = t[g + i * 4][a];
}

// ---------------- weight converts
// all six pointwise weights (w0,w2 of 3 branches) in one dispatch.
__global__ __launch_bounds__(256) void cast_all_kernel(
    const float* __restrict__ I0, const float* __restrict__ I1,
    const float* __restrict__ I2, const float* __restrict__ I3,
    const float* __restrict__ I4, const float* __restrict__ I5,
    unsigned short* __restrict__ O0, unsigned short* __restrict__ O1,
    unsigned short* __restrict__ O2, unsigned short* __restrict__ O3,
    unsigned short* __restrict__ O4, unsigned short* __restrict__ O5)
{
  const float* Is[6] = {I0, I1, I2, I3, I4, I5};
  unsigned short* Os[6] = {O0, O1, O2, O3, O4, O5};
  const float* I = Is[blockIdx.y];
  unsigned short* O = Os[blockIdx.y];
  const size_t i = ((size_t)blockIdx.x * 256 + threadIdx.x) * 4;
  const float4 v = *(const float4*)(I + i);
  us4 o; o.x = f2bf(v.x); o.y = f2bf(v.y); o.z = f2bf(v.z); o.w = f2bf(v.w);
  *(us4*)(O + i) = o;
}

// W1 [m][c][k] fp32 -> O [k][m][c] bf16
__global__ __launch_bounds__(256) void cast_w1_kernel(
    const float* __restrict__ W, unsigned short* __restrict__ O)
{
  const int c = blockIdx.x * 256 + threadIdx.x;
  const int m = blockIdx.y;
  const float* s = W + ((size_t)m * ICH + c) * KW;
#pragma unroll
  for (int k = 0; k < KW; ++k)
    O[((size_t)k * ICH + m) * ICH + c] = f2bf(s[k]);
}

// ---------------- 256x(BN) double-buffered MFMA GEMM, tap-outer causal shift
// (round-8 proven schedule; staging addresses hoisted: per-thread lane part
// loop-invariant, per-tile part wave-uniform scalar)
// OUTMODE: 0 = raw fp32; 1 = relu'd bf16 + fused column stats P1/P2; 2 = raw bf16.
template <int BN, int NTAPS, int OUTMODE>
__global__ __launch_bounds__(512, 2) void gemm256_kernel(
    const unsigned short* __restrict__ A, const unsigned short* __restrict__ W,
    void* __restrict__ Cv, int M, int K,
    float* __restrict__ P1, float* __restrict__ P2)
{
  extern __shared__ __align__(16) char lds[];
  constexpr int ABYTES = 32768;        // 256 rows x 128B
  constexpr int BBYTES = BN * 128;
  constexpr int BUF = ABYTES + BBYTES;
  constexpr int WN  = BN / 4;          // per-wave m extent (64 or 32)
  constexpr int JF  = BN / 64;         // j-frags per wave (4 or 2)
  constexpr int JF2 = BN / 128;        // j-frags per jh half (2 or 1)
  constexpr int NBQ = BN / 64;         // B staging quarters

  const int tid = threadIdx.x;
  const int ln  = tid & 63;
  const int wv  = tid >> 6;
  const int wr  = wv >> 2;             // s half (128 rows)
  const int wc  = wv & 3;              // m quarter (WN cols)
  const int l15 = ln & 15;
  const int lhi = ln >> 4;

  const int s0 = blockIdx.x * 256;
  const int m0 = blockIdx.y * BN;
  const int b  = blockIdx.z;

  const char* Ab = (const char*)(A + (size_t)b * RPAD * K);
  const char* Wb = (const char*)W;
  const size_t MK2 = (size_t)M * K * 2;
  const size_t K2  = (size_t)K * 2;
  const int KT = K >> 6;               // K-tiles of 64

  // staging: thread's linear LDS slot (row, col) -> pre-swizzled global col
  const int scs  = (((tid & 7) ^ ((tid >> 3) & 7)) << 4);
  // hoisted lane-invariant parts: row*K2 + scs (same row map for A and W)
  size_t lane_off[4];
#pragma unroll
  for (int q = 0; q < 4; ++q)
    lane_off[q] = (size_t)((q * 512 + tid) >> 3) * K2 + (size_t)scs;
  const int ldst = tid * 16;           // hoisted LDS dst lane offset
  // fragment reads: swizzled col bytes for k-slots 0,1
  const int rxor = (l15 & 7) << 4;
  const int cbx0 = (lhi * 16) ^ rxor;
  const int cbx1 = (lhi * 16 + 64) ^ rxor;

  f32x4 acc[8][JF] = {};

  auto STAGE = [&](int t, int k0, int pb) {
    const int roff = (NTAPS == 1) ? 4 : t;
    char* dst = lds + pb * BUF;
    const char* Au = Ab + (size_t)(s0 + roff) * K2 + (size_t)(k0 * 2);
    const char* Wu = Wb + (size_t)t * MK2 + (size_t)m0 * K2 + (size_t)(k0 * 2);
#pragma unroll
    for (int q = 0; q < 4; ++q)
      gload_lds16(Au + lane_off[q], dst + q * 8192 + ldst);
#pragma unroll
    for (int q = 0; q < NBQ; ++q)
      gload_lds16(Wu + lane_off[q], dst + ABYTES + q * 8192 + ldst);
  };

  auto COMPUTE = [&](int pb) {
    const char* bb = lds + pb * BUF;
    // hoisted B fragments: read once per tile, reused by both ih halves
    bf16x8 bw[2][JF2][2];
#pragma unroll
    for (int jh = 0; jh < 2; ++jh)
#pragma unroll
      for (int j = 0; j < JF2; ++j) {
        const int r = ABYTES + (wc * WN + jh * (WN / 2) + j * 16 + l15) * 128;
        bw[jh][j][0] = *(const bf16x8*)(bb + r + cbx0);
        bw[jh][j][1] = *(const bf16x8*)(bb + r + cbx1);
      }
#pragma unroll
    for (int ih = 0; ih < 2; ++ih) {
      bf16x8 af[4][2];
#pragma unroll
      for (int i = 0; i < 4; ++i) {
        const int r = (wr * 128 + ih * 64 + i * 16 + l15) * 128;
        af[i][0] = *(const bf16x8*)(bb + r + cbx0);
        af[i][1] = *(const bf16x8*)(bb + r + cbx1);
      }
#pragma unroll
      for (int jh = 0; jh < 2; ++jh) {
        __builtin_amdgcn_s_setprio(1);
#pragma unroll
        for (int i = 0; i < 4; ++i)
#pragma unroll
          for (int j = 0; j < JF2; ++j) {
            acc[ih * 4 + i][jh * JF2 + j] = __builtin_amdgcn_mfma_f32_16x16x32_bf16(
                af[i][0], bw[jh][j][0], acc[ih * 4 + i][jh * JF2 + j], 0, 0, 0);
            acc[ih * 4 + i][jh * JF2 + j] = __builtin_amdgcn_mfma_f32_16x16x32_bf16(
                af[i][1], bw[jh][j][1], acc[ih * 4 + i][jh * JF2 + j], 0, 0, 0);
          }
        __builtin_amdgcn_s_setprio(0);
      }
    }
  };

  STAGE(0, 0, 0);
  asm volatile("s_waitcnt vmcnt(0)" ::: "memory");
  __syncthreads();
  int p = 0;
  for (int t = 0; t < NTAPS; ++t) {
    for (int kt = 0; kt < KT; ++kt) {
      int ntp = t, nk = kt + 1;
      if (nk == KT) { nk = 0; ++ntp; }
      if (ntp < NTAPS) STAGE(ntp, nk * 64, p ^ 1);
      COMPUTE(p);
      asm volatile("s_waitcnt vmcnt(0)" ::: "memory");
      __syncthreads();
      p ^= 1;
    }
  }

  if constexpr (OUTMODE == 1) {
    // relu'd bf16 C + fused column partial sums (chunk = this block's 256 rows)
    unsigned short* Cb = (unsigned short*)Cv + (size_t)b * SEQ * M;
    float S[JF] = {}, Q[JF] = {};
#pragma unroll
    for (int i = 0; i < 8; ++i) {
      const int sb = s0 + wr * 128 + i * 16 + lhi * 4;
#pragma unroll
      for (int j = 0; j < JF; ++j) {
        const int m = m0 + wc * WN + j * 16 + l15;
#pragma unroll
        for (int r = 0; r < 4; ++r) {
          const float x = fmaxf(acc[i][j][r], 0.f);
          S[j] += x; Q[j] += x * x;
          Cb[(size_t)(sb + r) * M + m] = f2bf(x);
        }
      }
    }
#pragma unroll
    for (int j = 0; j < JF; ++j) {
      S[j] += __shfl_xor(S[j], 16, 64); S[j] += __shfl_xor(S[j], 32, 64);
      Q[j] += __shfl_xor(Q[j], 16, 64); Q[j] += __shfl_xor(Q[j], 32, 64);
    }
    float* SL = (float*)lds;                 // [2][4][JF][16]
    float* QL = SL + 2 * 4 * JF * 16;
    if (lhi == 0) {
#pragma unroll
      for (int j = 0; j < JF; ++j) {
        SL[((wr * 4 + wc) * JF + j) * 16 + l15] = S[j];
        QL[((wr * 4 + wc) * JF + j) * 16 + l15] = Q[j];
      }
    }
    __syncthreads();
    if (wr == 0 && lhi == 0) {
#pragma unroll
      for (int j = 0; j < JF; ++j) {
        const int m = m0 + wc * WN + j * 16 + l15;
        const size_t o = ((size_t)b * (SEQ / 256) + blockIdx.x) * M + m;
        P1[o] = SL[((0 * 4 + wc) * JF + j) * 16 + l15] +
                SL[((1 * 4 + wc) * JF + j) * 16 + l15];
        P2[o] = QL[((0 * 4 + wc) * JF + j) * 16 + l15] +
                QL[((1 * 4 + wc) * JF + j) * 16 + l15];
      }
    }
  } else if constexpr (OUTMODE == 2) {
    unsigned short* Cb = (unsigned short*)Cv + (size_t)b * SEQ * M;
#pragma unroll
    for (int i = 0; i < 8; ++i) {
      const int sb = s0 + wr * 128 + i * 16 + lhi * 4;
#pragma unroll
      for (int j = 0; j < JF; ++j) {
        const int m = m0 + wc * WN + j * 16 + l15;
#pragma unroll
        for (int r = 0; r < 4; ++r)
          Cb[(size_t)(sb + r) * M + m] = f2bf(acc[i][j][r]);
      }
    }
  } else {
    float* Cb = (float*)Cv + (size_t)b * SEQ * M;
#pragma unroll
    for (int i = 0; i < 8; ++i) {
      const int sb = s0 + wr * 128 + i * 16 + lhi * 4;
#pragma unroll
      for (int j = 0; j < JF; ++j) {
        const int m = m0 + wc * WN + j * 16 + l15;
#pragma unroll
        for (int r = 0; r < 4; ++r)
          Cb[(size_t)(sb + r) * M + m] = acc[i][j][r];
      }
    }
  }
}

// colfin: mean/scale per (b,m) from nchunk partials.  MS [b][2][M]
__global__ __launch_bounds__(256) void colfin_kernel(
    const float* __restrict__ P1, const float* __restrict__ P2,
    float* __restrict__ MS, int M, int nchunk)
{
  const int i = blockIdx.x * 256 + threadIdx.x;  // < BSZ*M
  const int b = i / M, m = i % M;
  float S1 = 0.f, S2 = 0.f;
  for (int c = 0; c < nchunk; ++c) {
    S1 += P1[((size_t)b * nchunk + c) * M + m];
    S2 += P2[((size_t)b * nchunk + c) * M + m];
  }
  const float mean = S1 * (1.f / SEQ);
  const float ss = fmaxf(S2 - SEQ * mean * mean, 0.f);
  const float scl = sqrtf((float)SEQ) / (sqrtf(ss) + EPSV);
  MS[((size_t)b * 2 + 0) * M + m] = mean;
  MS[((size_t)b * 2 + 1) * M + m] = scl;
}

// colapply (vectorized): (relu'd bf16 C - mean)*scl -> bf16 padded activation.
// thread = 8 consecutive m (short8); block = 8 s-rows; grid (SEQ/8, BSZ). M=ICH.
__global__ __launch_bounds__(256) void colapply_kernel(
    const unsigned short* __restrict__ Cf, const float* __restrict__ MS,
    unsigned short* __restrict__ Ob, int M)
{
  const int b = blockIdx.y;
  const int m0 = threadIdx.x * 8;
  if (m0 >= M) return;
  const int s0 = blockIdx.x * 8;
  float mean[8], scl[8];
  *(float4*)&mean[0] = *(const float4*)(MS + ((size_t)b * 2) * M + m0);
  *(float4*)&mean[4] = *(const float4*)(MS + ((size_t)b * 2) * M + m0 + 4);
  *(float4*)&scl[0]  = *(const float4*)(MS + ((size_t)b * 2 + 1) * M + m0);
  *(float4*)&scl[4]  = *(const float4*)(MS + ((size_t)b * 2 + 1) * M + m0 + 4);
  if (blockIdx.x == 0) {
    us8 z = {0, 0, 0, 0, 0, 0, 0, 0};
#pragma unroll
    for (int r = 0; r < 4; ++r)
      *(us8*)(Ob + ((size_t)b * RPAD + r) * M + m0) = z;
  }
#pragma unroll
  for (int r = 0; r < 8; ++r) {
    const int s = s0 + r;
    us8 v = *(const us8*)(Cf + ((size_t)b * SEQ + s) * M + m0);
    us8 o;
#pragma unroll
    for (int j = 0; j < 8; ++j)
      o[j] = f2bf((bf2f(v[j]) - mean[j]) * scl[j]);
    *(us8*)(Ob + ((size_t)b * RPAD + 4 + s) * M + m0) = o;
  }
}

// ---------------- cumsum over f (fast dim) + divide/scale(bf16)/shift(bf16)
// reads Df fp32, writes bf16 into Cc (free Cfb region)
__global__ __launch_bounds__(256) void combine_kernel(
    const float* __restrict__ Dp, const float* __restrict__ divT,
    const unsigned short* __restrict__ Sc, const unsigned short* __restrict__ Sh,
    unsigned short* __restrict__ Cc)
{
  const int row = blockIdx.x * 4 + (threadIdx.x >> 6);  // (b,s) flat
  const int b = row >> 11, s = row & 2047;
  const int ln = threadIdx.x & 63;
  const size_t base = ((size_t)b * SEQ + s) * FCH;
  const float* dv = divT + (size_t)s * FCH;
  float carry = 0.f;
  for (int c0 = 0; c0 < FCH; c0 += 64) {
    float x = Dp[base + c0 + ln];
#pragma unroll
    for (int d = 1; d < 64; d <<= 1) {
      const float t = __shfl_up(x, d, 64);
      if (ln >= d) x += t;
    }
    x += carry;
    carry = __shfl(x, 63, 64);
    Cc[base + c0 + ln] = f2bf(x / dv[c0 + ln] * bf2f(Sc[base + c0 + ln]) +
                              bf2f(Sh[base + c0 + ln]));
  }
}

// colred over bf16 Cc [b][s][FCH]: 16-row chunks, 128 chunks. grid (64, BSZ).
__global__ __launch_bounds__(256) void colred_bf_kernel(
    const unsigned short* __restrict__ Cf, float* __restrict__ P1,
    float* __restrict__ P2)
{
  const int b = blockIdx.y;
  const int m0 = (threadIdx.x & 127) * 8;
  const int half = threadIdx.x >> 7;
  const int chunk = blockIdx.x * 2 + half;   // 0..127
  const int sbeg = chunk * 16;
  float S[8] = {}, Q[8] = {};
  for (int r = 0; r < 16; ++r) {
    us8 v = *(const us8*)(Cf + ((size_t)b * SEQ + sbeg + r) * FCH + m0);
#pragma unroll
    for (int j = 0; j < 8; ++j) {
      const float x = fmaxf(bf2f(v[j]), 0.f);
      S[j] += x; Q[j] += x * x;
    }
  }
  float* p1 = P1 + ((size_t)b * 128 + chunk) * FCH + m0;
  float* p2 = P2 + ((size_t)b * 128 + chunk) * FCH + m0;
  *(float4*)p1 = *(const float4*)&S[0]; *(float4*)(p1 + 4) = *(const float4*)&S[4];
  *(float4*)p2 = *(const float4*)&Q[0]; *(float4*)(p2 + 4) = *(const float4*)&Q[4];
}

// ---------------- final apply: out[b][f][s] = inp + (relu(Cc)-mean)*scl, transposed
__global__ __launch_bounds__(256) void final_apply_kernel(
    const unsigned short* __restrict__ Cc, const float* __restrict__ MS,
    const float* __restrict__ inp, float* __restrict__ out)
{
  __shared__ float tile[64][65];
  const int b = blockIdx.z;
  const int s0 = blockIdx.x * 64, f0 = blockIdx.y * 64;
  const int a = threadIdx.x & 63, g = threadIdx.x >> 6;
  const float mean = MS[((size_t)b * 2 + 0) * FCH + f0 + a];
  const float scl  = MS[((size_t)b * 2 + 1) * FCH + f0 + a];
#pragma unroll
  for (int i = 0; i < 16; ++i) {
    const int s = g + i * 4;
    const float x =
        fmaxf(bf2f(Cc[((size_t)b * SEQ + s0 + s) * FCH + f0 + a]), 0.f);
    tile[s][a] = (x - mean) * scl;
  }
  __syncthreads();
#pragma unroll
  for (int i = 0; i < 16; ++i) {
    const int f = g + i * 4;
    const size_t o = ((size_t)b * FCH + f0 + f) * SEQ + s0 + a;
    out[o] = inp[o] + tile[a][f];
  }
}

extern "C" void kernel_launch(void* const* d_in, const int* in_sizes, int n_in,
                              void* d_out, int out_size, void* d_ws, size_t ws_size,
                              hipStream_t stream)
{
  const float* inp     = (const float*)d_in[0];
  const float* pos     = (const float*)d_in[1];
  const float* divisor = (const float*)d_in[2];
  const float* w_[9];
  for (int i = 0; i < 9; ++i) w_[i] = (const float*)d_in[3 + i];
  float* out = (float*)d_out;

  // workspace layout (~234 MB)
  char* p = (char*)d_ws;
  float*          divT = (float*)p;          p += (size_t)SEQ * FCH * 4;
  unsigned short* Xbf  = (unsigned short*)p; p += (size_t)BSZ * RPAD * FCH * 2;
  unsigned short* T0b  = (unsigned short*)p; p += (size_t)BSZ * RPAD * ICH * 2;
  unsigned short* Cfb  = (unsigned short*)p; p += (size_t)BSZ * SEQ * ICH * 2;
  float*          Df   = (float*)p;          p += (size_t)BSZ * SEQ * FCH * 4;
  unsigned short* Sfb  = (unsigned short*)p; p += (size_t)BSZ * SEQ * FCH * 2;
  unsigned short* Hfb  = (unsigned short*)p; p += (size_t)BSZ * SEQ * FCH * 2;
  unsigned short* w0b[3], *w2b[3];
  for (int i = 0; i < 3; ++i) {
    w0b[i] = (unsigned short*)p; p += (size_t)ICH * FCH * 2;
    w2b[i] = (unsigned short*)p; p += (size_t)FCH * ICH * 2;
  }
  unsigned short* w1b  = (unsigned short*)p; p += (size_t)KW * ICH * ICH * 2;
  float*          P1   = (float*)p;          p += (size_t)BSZ * 128 * FCH * 4;
  float*          P2   = (float*)p;          p += (size_t)BSZ * 128 * FCH * 4;
  float*          MS   = (float*)p;          p += (size_t)BSZ * 2 * ICH * 4;

  // allow >64KB dynamic LDS for the GEMM instantiations
  hipFuncSetAttribute((const void*)gemm256_kernel<256, 1, 1>,
                      hipFuncAttributeMaxDynamicSharedMemorySize, 131072);
  hipFuncSetAttribute((const void*)gemm256_kernel<256, 5, 1>,
                      hipFuncAttributeMaxDynamicSharedMemorySize, 131072);
  hipFuncSetAttribute((const void*)gemm256_kernel<128, 1, 0>,
                      hipFuncAttributeMaxDynamicSharedMemorySize, 98304);
  hipFuncSetAttribute((const void*)gemm256_kernel<128, 1, 2>,
                      hipFuncAttributeMaxDynamicSharedMemorySize, 98304);

  addpos_T_kernel<<<dim3(SEQ / 64, FCH / 64, BSZ), 256, 0, stream>>>(inp, pos, Xbf);
  transpose_div_kernel<<<dim3(SEQ / 64, FCH / 64), 256, 0, stream>>>(divisor, divT);
  // all six pointwise weight casts upfront in one dispatch
  cast_all_kernel<<<dim3((ICH * FCH) / 1024, 6), 256, 0, stream>>>(
      w_[0], w_[2], w_[3], w_[5], w_[6], w_[8],
      w0b[0], w2b[0], w0b[1], w2b[1], w0b[2], w2b[2]);

  // colfin+colapply after an OUTMODE=1 GEMM (stats already in P1/P2, 8 chunks)
  auto act_norm = [&]() {
    colfin_kernel<<<(BSZ * ICH) / 256, 256, 0, stream>>>(P1, P2, MS, ICH, 8);
    colapply_kernel<<<dim3(SEQ / 8, BSZ), 256, 0, stream>>>(Cfb, MS, T0b, ICH);
  };

  auto run_ff = [&](int br, const float* w1, void* dst, int mode2) {
    cast_w1_kernel<<<dim3(ICH / 256, ICH), 256, 0, stream>>>(w1, w1b);
    // conv0: M=ICH, K=FCH
    gemm256_kernel<256, 1, 1><<<dim3(SEQ / 256, ICH / 256, BSZ), 512, 131072, stream>>>(
        Xbf, w0b[br], Cfb, ICH, FCH, P1, P2);
    act_norm();
    // conv1: 5 causal taps (tap-outer), M=ICH, K=ICH
    gemm256_kernel<256, 5, 1><<<dim3(SEQ / 256, ICH / 256, BSZ), 512, 131072, stream>>>(
        T0b, w1b, Cfb, ICH, ICH, P1, P2);
    act_norm();
    // conv2: M=FCH, K=ICH; fp32 out for depth, bf16 for scale/shift
    if (mode2)
      gemm256_kernel<128, 1, 2><<<dim3(SEQ / 256, FCH / 128, BSZ), 512, 98304, stream>>>(
          T0b, w2b[br], dst, FCH, ICH, P1, P2);
    else
      gemm256_kernel<128, 1, 0><<<dim3(SEQ / 256, FCH / 128, BSZ), 512, 98304, stream>>>(
          T0b, w2b[br], dst, FCH, ICH, P1, P2);
  };

  run_ff(0, w_[1], Df, 0);   // depth (fp32, feeds cumsum)
  run_ff(1, w_[4], Sfb, 1);  // scale (bf16)
  run_ff(2, w_[7], Hfb, 1);  // shift (bf16)

  // combine -> bf16 into Cfb (free after shift branch)
  combine_kernel<<<(BSZ * SEQ) / 4, 256, 0, stream>>>(Df, divT, Sfb, Hfb, Cfb);

  // final act_norm over s (per (b,f)) on Cfb, then transpose + residual
  colred_bf_kernel<<<dim3(64, BSZ), 256, 0, stream>>>(Cfb, P1, P2);
  colfin_kernel<<<(BSZ * FCH) / 256, 256, 0, stream>>>(P1, P2, MS, FCH, 128);
  final_apply_kernel<<<dim3(SEQ / 64, FCH / 64, BSZ), 256, 0, stream>>>(
      Cfb, MS, inp, out);
}

// Round 13
// 1183.290 us; speedup vs baseline: 1.0268x; 1.0268x over previous
//
#include <hip/hip_runtime.h>
#include <math.h>

#define BSZ 4
#define FCH 1024
#define SEQ 2048
#define ICH 2048
#define KW  5
#define EPSV 1e-5f
#define RPAD 2244   // 4 front zero-pad + 2048 rows + slack

typedef __attribute__((ext_vector_type(8))) short bf16x8;
typedef __attribute__((ext_vector_type(4))) float f32x4;
typedef __attribute__((ext_vector_type(4))) unsigned short us4;
typedef __attribute__((ext_vector_type(8))) unsigned short us8;

__device__ __forceinline__ unsigned short f2bf(float f) {
  union { float f; unsigned u; } v; v.f = f;
  unsigned r = v.u + 0x7fff + ((v.u >> 16) & 1);  // round-to-nearest-even
  return (unsigned short)(r >> 16);
}
__device__ __forceinline__ float bf2f(unsigned short u) {
  union { unsigned u; float f; } v; v.u = (unsigned)u << 16; return v.f;
}

__device__ __forceinline__ void gload_lds16(const void* g, void* l) {
  __builtin_amdgcn_global_load_lds(
      (const __attribute__((address_space(1))) void*)g,
      (__attribute__((address_space(3))) void*)l, 16, 0, 0);
}

// ---------------- input transpose + pos add:  [b][f][s] -> bf16 [b][4+s][f]
// pad rows 0..3 zeroed by the s0==0 blocks (fused zero_xpad).
__global__ __launch_bounds__(256) void addpos_T_kernel(
    const float* __restrict__ inp, const float* __restrict__ pos,
    unsigned short* __restrict__ X)
{
  __shared__ float t[64][65];
  const int s0 = blockIdx.x * 64, f0 = blockIdx.y * 64, b = blockIdx.z;
  const int a = threadIdx.x & 63, g = threadIdx.x >> 6;
  const float* ib = inp + (size_t)b * FCH * SEQ;
#pragma unroll
  for (int i = 0; i < 16; ++i) {
    const size_t o = (size_t)(f0 + g + i * 4) * SEQ + s0 + a;
    t[a][g + i * 4] = ib[o] + pos[o];
  }
  if (blockIdx.x == 0 && g == 0) {
#pragma unroll
    for (int r = 0; r < 4; ++r)
      X[(size_t)b * RPAD * FCH + (size_t)r * FCH + f0 + a] = 0;
  }
  __syncthreads();
#pragma unroll
  for (int i = 0; i < 16; ++i)
    X[(size_t)b * RPAD * FCH + (size_t)(4 + s0 + g + i * 4) * FCH + f0 + a] =
        f2bf(t[g + i * 4][a]);
}

// divisor [f][s] -> divT [s][f] fp32
__global__ __launch_bounds__(256) void transpose_div_kernel(
    const float* __restrict__ D, float* __restrict__ O)
{
  __shared__ float t[64][65];
  const int s0 = blockIdx.x * 64, f0 = blockIdx.y * 64;
  const int a = threadIdx.x & 63, g = threadIdx.x >> 6;
#pragma unroll
  for (int i = 0; i < 16; ++i)
    t[a][g + i * 4] = D[(size_t)(f0 + g + i * 4) * SEQ + s0 + a];
  __syncthreads();
#pragma unroll
  for (int i = 0; i < 16; ++i)
    O[(size_t)(s0 + g + i * 4) * FCH + f0 + a] = t[g + i * 4][a];
}

// ---------------- weight converts
// all six pointwise weights (w0,w2 of 3 branches) in one dispatch.
__global__ __launch_bounds__(256) void cast_all_kernel(
    const float* __restrict__ I0, const float* __restrict__ I1,
    const float* __restrict__ I2, const float* __restrict__ I3,
    const float* __restrict__ I4, const float* __restrict__ I5,
    unsigned short* __restrict__ O0, unsigned short* __restrict__ O1,
    unsigned short* __restrict__ O2, unsigned short* __restrict__ O3,
    unsigned short* __restrict__ O4, unsigned short* __restrict__ O5)
{
  const float* Is[6] = {I0, I1, I2, I3, I4, I5};
  unsigned short* Os[6] = {O0, O1, O2, O3, O4, O5};
  const float* I = Is[blockIdx.y];
  unsigned short* O = Os[blockIdx.y];
  const size_t i = ((size_t)blockIdx.x * 256 + threadIdx.x) * 4;
  const float4 v = *(const float4*)(I + i);
  us4 o; o.x = f2bf(v.x); o.y = f2bf(v.y); o.z = f2bf(v.z); o.w = f2bf(v.w);
  *(us4*)(O + i) = o;
}

// W1 [m][c][k] fp32 -> O [k][m][c] bf16
__global__ __launch_bounds__(256) void cast_w1_kernel(
    const float* __restrict__ W, unsigned short* __restrict__ O)
{
  const int c = blockIdx.x * 256 + threadIdx.x;
  const int m = blockIdx.y;
  const float* s = W + ((size_t)m * ICH + c) * KW;
#pragma unroll
  for (int k = 0; k < KW; ++k)
    O[((size_t)k * ICH + m) * ICH + c] = f2bf(s[k]);
}

// ---------------- 256x(BN) double-buffered MFMA GEMM, tap-outer causal shift
// (round-8 proven schedule + r12 address hoisting; setprio removed per m190:
// priority boost is ~0/negative on lockstep non-phase-split structures)
// OUTMODE: 0 = raw fp32; 1 = relu'd bf16 + fused column stats P1/P2; 2 = raw bf16.
template <int BN, int NTAPS, int OUTMODE>
__global__ __launch_bounds__(512, 2) void gemm256_kernel(
    const unsigned short* __restrict__ A, const unsigned short* __restrict__ W,
    void* __restrict__ Cv, int M, int K,
    float* __restrict__ P1, float* __restrict__ P2)
{
  extern __shared__ __align__(16) char lds[];
  constexpr int ABYTES = 32768;        // 256 rows x 128B
  constexpr int BBYTES = BN * 128;
  constexpr int BUF = ABYTES + BBYTES;
  constexpr int WN  = BN / 4;          // per-wave m extent (64 or 32)
  constexpr int JF  = BN / 64;         // j-frags per wave (4 or 2)
  constexpr int JF2 = BN / 128;        // j-frags per jh half (2 or 1)
  constexpr int NBQ = BN / 64;         // B staging quarters

  const int tid = threadIdx.x;
  const int ln  = tid & 63;
  const int wv  = tid >> 6;
  const int wr  = wv >> 2;             // s half (128 rows)
  const int wc  = wv & 3;              // m quarter (WN cols)
  const int l15 = ln & 15;
  const int lhi = ln >> 4;

  const int s0 = blockIdx.x * 256;
  const int m0 = blockIdx.y * BN;
  const int b  = blockIdx.z;

  const char* Ab = (const char*)(A + (size_t)b * RPAD * K);
  const char* Wb = (const char*)W;
  const size_t MK2 = (size_t)M * K * 2;
  const size_t K2  = (size_t)K * 2;
  const int KT = K >> 6;               // K-tiles of 64

  // staging: thread's linear LDS slot (row, col) -> pre-swizzled global col
  const int scs  = (((tid & 7) ^ ((tid >> 3) & 7)) << 4);
  // hoisted lane-invariant parts: row*K2 + scs (same row map for A and W)
  size_t lane_off[4];
#pragma unroll
  for (int q = 0; q < 4; ++q)
    lane_off[q] = (size_t)((q * 512 + tid) >> 3) * K2 + (size_t)scs;
  const int ldst = tid * 16;           // hoisted LDS dst lane offset
  // fragment reads: swizzled col bytes for k-slots 0,1
  const int rxor = (l15 & 7) << 4;
  const int cbx0 = (lhi * 16) ^ rxor;
  const int cbx1 = (lhi * 16 + 64) ^ rxor;

  f32x4 acc[8][JF] = {};

  auto STAGE = [&](int t, int k0, int pb) {
    const int roff = (NTAPS == 1) ? 4 : t;
    char* dst = lds + pb * BUF;
    const char* Au = Ab + (size_t)(s0 + roff) * K2 + (size_t)(k0 * 2);
    const char* Wu = Wb + (size_t)t * MK2 + (size_t)m0 * K2 + (size_t)(k0 * 2);
#pragma unroll
    for (int q = 0; q < 4; ++q)
      gload_lds16(Au + lane_off[q], dst + q * 8192 + ldst);
#pragma unroll
    for (int q = 0; q < NBQ; ++q)
      gload_lds16(Wu + lane_off[q], dst + ABYTES + q * 8192 + ldst);
  };

  auto COMPUTE = [&](int pb) {
    const char* bb = lds + pb * BUF;
    // hoisted B fragments: read once per tile, reused by both ih halves
    bf16x8 bw[2][JF2][2];
#pragma unroll
    for (int jh = 0; jh < 2; ++jh)
#pragma unroll
      for (int j = 0; j < JF2; ++j) {
        const int r = ABYTES + (wc * WN + jh * (WN / 2) + j * 16 + l15) * 128;
        bw[jh][j][0] = *(const bf16x8*)(bb + r + cbx0);
        bw[jh][j][1] = *(const bf16x8*)(bb + r + cbx1);
      }
#pragma unroll
    for (int ih = 0; ih < 2; ++ih) {
      bf16x8 af[4][2];
#pragma unroll
      for (int i = 0; i < 4; ++i) {
        const int r = (wr * 128 + ih * 64 + i * 16 + l15) * 128;
        af[i][0] = *(const bf16x8*)(bb + r + cbx0);
        af[i][1] = *(const bf16x8*)(bb + r + cbx1);
      }
#pragma unroll
      for (int jh = 0; jh < 2; ++jh) {
#pragma unroll
        for (int i = 0; i < 4; ++i)
#pragma unroll
          for (int j = 0; j < JF2; ++j) {
            acc[ih * 4 + i][jh * JF2 + j] = __builtin_amdgcn_mfma_f32_16x16x32_bf16(
                af[i][0], bw[jh][j][0], acc[ih * 4 + i][jh * JF2 + j], 0, 0, 0);
            acc[ih * 4 + i][jh * JF2 + j] = __builtin_amdgcn_mfma_f32_16x16x32_bf16(
                af[i][1], bw[jh][j][1], acc[ih * 4 + i][jh * JF2 + j], 0, 0, 0);
          }
      }
    }
  };

  STAGE(0, 0, 0);
  asm volatile("s_waitcnt vmcnt(0)" ::: "memory");
  __syncthreads();
  int p = 0;
  for (int t = 0; t < NTAPS; ++t) {
    for (int kt = 0; kt < KT; ++kt) {
      int ntp = t, nk = kt + 1;
      if (nk == KT) { nk = 0; ++ntp; }
      if (ntp < NTAPS) STAGE(ntp, nk * 64, p ^ 1);
      COMPUTE(p);
      asm volatile("s_waitcnt vmcnt(0)" ::: "memory");
      __syncthreads();
      p ^= 1;
    }
  }

  if constexpr (OUTMODE == 1) {
    // relu'd bf16 C + fused column partial sums (chunk = this block's 256 rows)
    unsigned short* Cb = (unsigned short*)Cv + (size_t)b * SEQ * M;
    float S[JF] = {}, Q[JF] = {};
#pragma unroll
    for (int i = 0; i < 8; ++i) {
      const int sb = s0 + wr * 128 + i * 16 + lhi * 4;
#pragma unroll
      for (int j = 0; j < JF; ++j) {
        const int m = m0 + wc * WN + j * 16 + l15;
#pragma unroll
        for (int r = 0; r < 4; ++r) {
          const float x = fmaxf(acc[i][j][r], 0.f);
          S[j] += x; Q[j] += x * x;
          Cb[(size_t)(sb + r) * M + m] = f2bf(x);
        }
      }
    }
#pragma unroll
    for (int j = 0; j < JF; ++j) {
      S[j] += __shfl_xor(S[j], 16, 64); S[j] += __shfl_xor(S[j], 32, 64);
      Q[j] += __shfl_xor(Q[j], 16, 64); Q[j] += __shfl_xor(Q[j], 32, 64);
    }
    float* SL = (float*)lds;                 // [2][4][JF][16]
    float* QL = SL + 2 * 4 * JF * 16;
    if (lhi == 0) {
#pragma unroll
      for (int j = 0; j < JF; ++j) {
        SL[((wr * 4 + wc) * JF + j) * 16 + l15] = S[j];
        QL[((wr * 4 + wc) * JF + j) * 16 + l15] = Q[j];
      }
    }
    __syncthreads();
    if (wr == 0 && lhi == 0) {
#pragma unroll
      for (int j = 0; j < JF; ++j) {
        const int m = m0 + wc * WN + j * 16 + l15;
        const size_t o = ((size_t)b * (SEQ / 256) + blockIdx.x) * M + m;
        P1[o] = SL[((0 * 4 + wc) * JF + j) * 16 + l15] +
                SL[((1 * 4 + wc) * JF + j) * 16 + l15];
        P2[o] = QL[((0 * 4 + wc) * JF + j) * 16 + l15] +
                QL[((1 * 4 + wc) * JF + j) * 16 + l15];
      }
    }
  } else if constexpr (OUTMODE == 2) {
    unsigned short* Cb = (unsigned short*)Cv + (size_t)b * SEQ * M;
#pragma unroll
    for (int i = 0; i < 8; ++i) {
      const int sb = s0 + wr * 128 + i * 16 + lhi * 4;
#pragma unroll
      for (int j = 0; j < JF; ++j) {
        const int m = m0 + wc * WN + j * 16 + l15;
#pragma unroll
        for (int r = 0; r < 4; ++r)
          Cb[(size_t)(sb + r) * M + m] = f2bf(acc[i][j][r]);
      }
    }
  } else {
    float* Cb = (float*)Cv + (size_t)b * SEQ * M;
#pragma unroll
    for (int i = 0; i < 8; ++i) {
      const int sb = s0 + wr * 128 + i * 16 + lhi * 4;
#pragma unroll
      for (int j = 0; j < JF; ++j) {
        const int m = m0 + wc * WN + j * 16 + l15;
#pragma unroll
        for (int r = 0; r < 4; ++r)
          Cb[(size_t)(sb + r) * M + m] = acc[i][j][r];
      }
    }
  }
}

// colfin: mean/scale per (b,m) from nchunk partials.  MS [b][2][M]
__global__ __launch_bounds__(256) void colfin_kernel(
    const float* __restrict__ P1, const float* __restrict__ P2,
    float* __restrict__ MS, int M, int nchunk)
{
  const int i = blockIdx.x * 256 + threadIdx.x;  // < BSZ*M
  const int b = i / M, m = i % M;
  float S1 = 0.f, S2 = 0.f;
  for (int c = 0; c < nchunk; ++c) {
    S1 += P1[((size_t)b * nchunk + c) * M + m];
    S2 += P2[((size_t)b * nchunk + c) * M + m];
  }
  const float mean = S1 * (1.f / SEQ);
  const float ss = fmaxf(S2 - SEQ * mean * mean, 0.f);
  const float scl = sqrtf((float)SEQ) / (sqrtf(ss) + EPSV);
  MS[((size_t)b * 2 + 0) * M + m] = mean;
  MS[((size_t)b * 2 + 1) * M + m] = scl;
}

// colapply (vectorized): (relu'd bf16 C - mean)*scl -> bf16 padded activation.
// thread = 8 consecutive m (short8); block = 8 s-rows; grid (SEQ/8, BSZ). M=ICH.
__global__ __launch_bounds__(256) void colapply_kernel(
    const unsigned short* __restrict__ Cf, const float* __restrict__ MS,
    unsigned short* __restrict__ Ob, int M)
{
  const int b = blockIdx.y;
  const int m0 = threadIdx.x * 8;
  if (m0 >= M) return;
  const int s0 = blockIdx.x * 8;
  float mean[8], scl[8];
  *(float4*)&mean[0] = *(const float4*)(MS + ((size_t)b * 2) * M + m0);
  *(float4*)&mean[4] = *(const float4*)(MS + ((size_t)b * 2) * M + m0 + 4);
  *(float4*)&scl[0]  = *(const float4*)(MS + ((size_t)b * 2 + 1) * M + m0);
  *(float4*)&scl[4]  = *(const float4*)(MS + ((size_t)b * 2 + 1) * M + m0 + 4);
  if (blockIdx.x == 0) {
    us8 z = {0, 0, 0, 0, 0, 0, 0, 0};
#pragma unroll
    for (int r = 0; r < 4; ++r)
      *(us8*)(Ob + ((size_t)b * RPAD + r) * M + m0) = z;
  }
#pragma unroll
  for (int r = 0; r < 8; ++r) {
    const int s = s0 + r;
    us8 v = *(const us8*)(Cf + ((size_t)b * SEQ + s) * M + m0);
    us8 o;
#pragma unroll
    for (int j = 0; j < 8; ++j)
      o[j] = f2bf((bf2f(v[j]) - mean[j]) * scl[j]);
    *(us8*)(Ob + ((size_t)b * RPAD + 4 + s) * M + m0) = o;
  }
}

// ---------------- cumsum over f (fast dim) + divide/scale(bf16)/shift(bf16)
// float4 per lane: lane owns 4 consecutive f; local prefix + wave scan; 4 chunks.
__global__ __launch_bounds__(256) void combine_kernel(
    const float* __restrict__ Dp, const float* __restrict__ divT,
    const unsigned short* __restrict__ Sc, const unsigned short* __restrict__ Sh,
    unsigned short* __restrict__ Cc)
{
  const int row = blockIdx.x * 4 + (threadIdx.x >> 6);  // (b,s) flat
  const int b = row >> 11, s = row & 2047;
  const int ln = threadIdx.x & 63;
  const size_t base = ((size_t)b * SEQ + s) * FCH;
  const float* dv = divT + (size_t)s * FCH;
  float carry = 0.f;
  for (int c0 = 0; c0 < FCH; c0 += 256) {
    const int f = c0 + ln * 4;
    const float4 v = *(const float4*)(Dp + base + f);
    // local inclusive prefix over the 4 elements
    const float p0 = v.x, p1 = p0 + v.y, p2 = p1 + v.z, p3 = p2 + v.w;
    // wave-inclusive scan of lane totals
    float inc = p3;
#pragma unroll
    for (int d = 1; d < 64; d <<= 1) {
      const float t = __shfl_up(inc, d, 64);
      if (ln >= d) inc += t;
    }
    const float excl = inc - p3 + carry;  // exclusive prefix for this lane
    carry += __shfl(inc, 63, 64);
    const float4 dvv = *(const float4*)(dv + f);
    const us4 sc = *(const us4*)(Sc + base + f);
    const us4 sh = *(const us4*)(Sh + base + f);
    us4 o;
    o.x = f2bf((excl + p0) / dvv.x * bf2f(sc.x) + bf2f(sh.x));
    o.y = f2bf((excl + p1) / dvv.y * bf2f(sc.y) + bf2f(sh.y));
    o.z = f2bf((excl + p2) / dvv.z * bf2f(sc.z) + bf2f(sh.z));
    o.w = f2bf((excl + p3) / dvv.w * bf2f(sc.w) + bf2f(sh.w));
    *(us4*)(Cc + base + f) = o;
  }
}

// colred over bf16 Cc [b][s][FCH]: 16-row chunks, 128 chunks. grid (64, BSZ).
__global__ __launch_bounds__(256) void colred_bf_kernel(
    const unsigned short* __restrict__ Cf, float* __restrict__ P1,
    float* __restrict__ P2)
{
  const int b = blockIdx.y;
  const int m0 = (threadIdx.x & 127) * 8;
  const int half = threadIdx.x >> 7;
  const int chunk = blockIdx.x * 2 + half;   // 0..127
  const int sbeg = chunk * 16;
  float S[8] = {}, Q[8] = {};
  for (int r = 0; r < 16; ++r) {
    us8 v = *(const us8*)(Cf + ((size_t)b * SEQ + sbeg + r) * FCH + m0);
#pragma unroll
    for (int j = 0; j < 8; ++j) {
      const float x = fmaxf(bf2f(v[j]), 0.f);
      S[j] += x; Q[j] += x * x;
    }
  }
  float* p1 = P1 + ((size_t)b * 128 + chunk) * FCH + m0;
  float* p2 = P2 + ((size_t)b * 128 + chunk) * FCH + m0;
  *(float4*)p1 = *(const float4*)&S[0]; *(float4*)(p1 + 4) = *(const float4*)&S[4];
  *(float4*)p2 = *(const float4*)&Q[0]; *(float4*)(p2 + 4) = *(const float4*)&Q[4];
}

// ---------------- final apply: out[b][f][s] = inp + (relu(Cc)-mean)*scl, transposed
__global__ __launch_bounds__(256) void final_apply_kernel(
    const unsigned short* __restrict__ Cc, const float* __restrict__ MS,
    const float* __restrict__ inp, float* __restrict__ out)
{
  __shared__ float tile[64][65];
  const int b = blockIdx.z;
  const int s0 = blockIdx.x * 64, f0 = blockIdx.y * 64;
  const int a = threadIdx.x & 63, g = threadIdx.x >> 6;
  const float mean = MS[((size_t)b * 2 + 0) * FCH + f0 + a];
  const float scl  = MS[((size_t)b * 2 + 1) * FCH + f0 + a];
#pragma unroll
  for (int i = 0; i < 16; ++i) {
    const int s = g + i * 4;
    const float x =
        fmaxf(bf2f(Cc[((size_t)b * SEQ + s0 + s) * FCH + f0 + a]), 0.f);
    tile[s][a] = (x - mean) * scl;
  }
  __syncthreads();
#pragma unroll
  for (int i = 0; i < 16; ++i) {
    const int f = g + i * 4;
    const size_t o = ((size_t)b * FCH + f0 + f) * SEQ + s0 + a;
    out[o] = inp[o] + tile[a][f];
  }
}

extern "C" void kernel_launch(void* const* d_in, const int* in_sizes, int n_in,
                              void* d_out, int out_size, void* d_ws, size_t ws_size,
                              hipStream_t stream)
{
  const float* inp     = (const float*)d_in[0];
  const float* pos     = (const float*)d_in[1];
  const float* divisor = (const float*)d_in[2];
  const float* w_[9];
  for (int i = 0; i < 9; ++i) w_[i] = (const float*)d_in[3 + i];
  float* out = (float*)d_out;

  // workspace layout (~234 MB)
  char* p = (char*)d_ws;
  float*          divT = (float*)p;          p += (size_t)SEQ * FCH * 4;
  unsigned short* Xbf  = (unsigned short*)p; p += (size_t)BSZ * RPAD * FCH * 2;
  unsigned short* T0b  = (unsigned short*)p; p += (size_t)BSZ * RPAD * ICH * 2;
  unsigned short* Cfb  = (unsigned short*)p; p += (size_t)BSZ * SEQ * ICH * 2;
  float*          Df   = (float*)p;          p += (size_t)BSZ * SEQ * FCH * 4;
  unsigned short* Sfb  = (unsigned short*)p; p += (size_t)BSZ * SEQ * FCH * 2;
  unsigned short* Hfb  = (unsigned short*)p; p += (size_t)BSZ * SEQ * FCH * 2;
  unsigned short* w0b[3], *w2b[3];
  for (int i = 0; i < 3; ++i) {
    w0b[i] = (unsigned short*)p; p += (size_t)ICH * FCH * 2;
    w2b[i] = (unsigned short*)p; p += (size_t)FCH * ICH * 2;
  }
  unsigned short* w1b  = (unsigned short*)p; p += (size_t)KW * ICH * ICH * 2;
  float*          P1   = (float*)p;          p += (size_t)BSZ * 128 * FCH * 4;
  float*          P2   = (float*)p;          p += (size_t)BSZ * 128 * FCH * 4;
  float*          MS   = (float*)p;          p += (size_t)BSZ * 2 * ICH * 4;

  // allow >64KB dynamic LDS for the GEMM instantiations
  hipFuncSetAttribute((const void*)gemm256_kernel<256, 1, 1>,
                      hipFuncAttributeMaxDynamicSharedMemorySize, 131072);
  hipFuncSetAttribute((const void*)gemm256_kernel<256, 5, 1>,
                      hipFuncAttributeMaxDynamicSharedMemorySize, 131072);
  hipFuncSetAttribute((const void*)gemm256_kernel<128, 1, 0>,
                      hipFuncAttributeMaxDynamicSharedMemorySize, 98304);
  hipFuncSetAttribute((const void*)gemm256_kernel<128, 1, 2>,
                      hipFuncAttributeMaxDynamicSharedMemorySize, 98304);

  addpos_T_kernel<<<dim3(SEQ / 64, FCH / 64, BSZ), 256, 0, stream>>>(inp, pos, Xbf);
  transpose_div_kernel<<<dim3(SEQ / 64, FCH / 64), 256, 0, stream>>>(divisor, divT);
  // all six pointwise weight casts upfront in one dispatch
  cast_all_kernel<<<dim3((ICH * FCH) / 1024, 6), 256, 0, stream>>>(
      w_[0], w_[2], w_[3], w_[5], w_[6], w_[8],
      w0b[0], w2b[0], w0b[1], w2b[1], w0b[2], w2b[2]);

  // colfin+colapply after an OUTMODE=1 GEMM (stats already in P1/P2, 8 chunks)
  auto act_norm = [&]() {
    colfin_kernel<<<(BSZ * ICH) / 256, 256, 0, stream>>>(P1, P2, MS, ICH, 8);
    colapply_kernel<<<dim3(SEQ / 8, BSZ), 256, 0, stream>>>(Cfb, MS, T0b, ICH);
  };

  auto run_ff = [&](int br, const float* w1, void* dst, int mode2) {
    cast_w1_kernel<<<dim3(ICH / 256, ICH), 256, 0, stream>>>(w1, w1b);
    // conv0: M=ICH, K=FCH
    gemm256_kernel<256, 1, 1><<<dim3(SEQ / 256, ICH / 256, BSZ), 512, 131072, stream>>>(
        Xbf, w0b[br], Cfb, ICH, FCH, P1, P2);
    act_norm();
    // conv1: 5 causal taps (tap-outer), M=ICH, K=ICH
    gemm256_kernel<256, 5, 1><<<dim3(SEQ / 256, ICH / 256, BSZ), 512, 131072, stream>>>(
        T0b, w1b, Cfb, ICH, ICH, P1, P2);
    act_norm();
    // conv2: M=FCH, K=ICH; fp32 out for depth, bf16 for scale/shift
    if (mode2)
      gemm256_kernel<128, 1, 2><<<dim3(SEQ / 256, FCH / 128, BSZ), 512, 98304, stream>>>(
          T0b, w2b[br], dst, FCH, ICH, P1, P2);
    else
      gemm256_kernel<128, 1, 0><<<dim3(SEQ / 256, FCH / 128, BSZ), 512, 98304, stream>>>(
          T0b, w2b[br], dst, FCH, ICH, P1, P2);
  };

  run_ff(0, w_[1], Df, 0);   // depth (fp32, feeds cumsum)
  run_ff(1, w_[4], Sfb, 1);  // scale (bf16)
  run_ff(2, w_[7], Hfb, 1);  // shift (bf16)

  // combine -> bf16 into Cfb (free after shift branch)
  combine_kernel<<<(BSZ * SEQ) / 4, 256, 0, stream>>>(Df, divT, Sfb, Hfb, Cfb);

  // final act_norm over s (per (b,f)) on Cfb, then transpose + residual
  colred_bf_kernel<<<dim3(64, BSZ), 256, 0, stream>>>(Cfb, P1, P2);
  colfin_kernel<<<(BSZ * FCH) / 256, 256, 0, stream>>>(P1, P2, MS, FCH, 128);
  final_apply_kernel<<<dim3(SEQ / 64, FCH / 64, BSZ), 256, 0, stream>>>(
      Cfb, MS, inp, out);
}